// Round 1
// baseline (114.438 us; speedup 1.0000x reference)
//
#include <hip/hip_runtime.h>
#include <math.h>

// Order-10 Gauss-Legendre quadrature on [-1,1], with the affine map
// t = 0.5*(x+1) pre-folded into the node table (t in (0,1)).
#define GL_ORDER 10

__device__ __forceinline__ float lc_one(float b_in, float z, float r,
                                        float u0, float u1, float inv_norm,
                                        const float* tj, const float* wj) {
    const float bb = fabsf(b_in);

    // fully-occulted core: rho in [0, clip(r-b, 0, 1)]
    const float core_hi = fminf(fmaxf(r - bb, 0.0f), 1.0f);

    // partially-occulted annulus: rho in [clip(|b-r|,0,1), clip(b+r,0,1)]
    const float lo    = fminf(fabsf(bb - r), 1.0f);
    const float hi    = fminf(bb + r, 1.0f);
    const float width = fmaxf(hi - lo, 0.0f);

    const float b2r2 = bb * bb - r * r;
    const float twob = 2.0f * bb;

    float s_core = 0.0f;
    float s_ann  = 0.0f;

#pragma unroll
    for (int j = 0; j < GL_ORDER; ++j) {
        const float t = tj[j];

        // ---- core node ----
        const float rc   = core_hi * t;
        const float muc  = sqrtf(fmaxf(1.0f - rc * rc, 1e-12f));
        const float ommc = 1.0f - muc;
        const float Ic   = 1.0f - ommc * (u0 + u1 * ommc);  // 1 - u0*omm - u1*omm^2
        s_core = fmaf(wj[j] * Ic, rc, s_core);

        // ---- annulus node ----
        const float ra   = fmaf(width, t, lo);
        const float mua  = sqrtf(fmaxf(1.0f - ra * ra, 1e-12f));
        const float omma = 1.0f - mua;
        const float Ia   = 1.0f - omma * (u0 + u1 * omma);

        const float denom = twob * ra;
        const bool  safe  = denom > 1e-12f;
        float cosarg = safe ? (b2r2 + ra * ra) / denom : 0.0f;
        cosarg = fminf(fmaxf(cosarg, -0.999999f), 0.999999f);
        const float alpha = safe ? 2.0f * acosf(cosarg) : 0.0f;

        s_ann = fmaf(wj[j] * Ia * alpha, ra, s_ann);
    }

    const float f_core = 0.5f * core_hi * 6.28318530717958647692f * s_core;
    const float f_ann  = 0.5f * width * s_ann;
    const float lc     = -(f_core + f_ann) * inv_norm;
    return (z > 0.0f) ? lc : 0.0f;
}

__global__ __launch_bounds__(256) void LimbDarkLightCurve_55370718380097_kernel(
    const float* __restrict__ u, const float* __restrict__ bptr,
    const float* __restrict__ rptr, const float* __restrict__ zptr,
    float* __restrict__ out, int K) {
    // Order-10 GL nodes mapped to t = 0.5*(x+1); weights as-is.
    const float tj[GL_ORDER] = {
        0.013046735741414128f, 0.067468316655507744f, 0.160295215850487787f,
        0.283302302935376393f, 0.425562830509184362f, 0.574437169490815638f,
        0.716697697064623607f, 0.839704784149512213f, 0.932531683344492256f,
        0.986953264258585872f};
    const float wj[GL_ORDER] = {
        0.066671344308688138f, 0.149451349150580593f, 0.219086362515982044f,
        0.269266719309996355f, 0.295524224714752870f, 0.295524224714752870f,
        0.269266719309996355f, 0.219086362515982044f, 0.149451349150580593f,
        0.066671344308688138f};

    const float u0 = u[0];
    const float u1 = u[1];
    const float r  = rptr[0];
    // norm = pi * (1 - u0*2/(2*3) - u1*2/(3*4)) = pi * (1 - u0/3 - u1/6)
    const float inv_norm =
        1.0f / (3.14159265358979323846f * (1.0f - u0 * (1.0f / 3.0f) - u1 * (1.0f / 6.0f)));

    const int i4 = (blockIdx.x * blockDim.x + threadIdx.x) * 4;
    if (i4 + 3 < K) {
        const float4 b4 = *reinterpret_cast<const float4*>(bptr + i4);
        const float4 z4 = *reinterpret_cast<const float4*>(zptr + i4);
        float4 o;
        o.x = lc_one(b4.x, z4.x, r, u0, u1, inv_norm, tj, wj);
        o.y = lc_one(b4.y, z4.y, r, u0, u1, inv_norm, tj, wj);
        o.z = lc_one(b4.z, z4.z, r, u0, u1, inv_norm, tj, wj);
        o.w = lc_one(b4.w, z4.w, r, u0, u1, inv_norm, tj, wj);
        *reinterpret_cast<float4*>(out + i4) = o;
    } else {
        for (int i = i4; i < K; ++i) {
            out[i] = lc_one(bptr[i], zptr[i], r, u0, u1, inv_norm, tj, wj);
        }
    }
}

extern "C" void kernel_launch(void* const* d_in, const int* in_sizes, int n_in,
                              void* d_out, int out_size, void* d_ws, size_t ws_size,
                              hipStream_t stream) {
    const float* u = (const float*)d_in[0];
    const float* b = (const float*)d_in[1];
    const float* r = (const float*)d_in[2];
    const float* z = (const float*)d_in[3];
    float* out = (float*)d_out;
    const int K = in_sizes[1];

    const int elems_per_thread = 4;
    const int block = 256;
    const int threads_needed = (K + elems_per_thread - 1) / elems_per_thread;
    const int grid = (threads_needed + block - 1) / block;
    LimbDarkLightCurve_55370718380097_kernel<<<grid, block, 0, stream>>>(
        u, b, r, z, out, K);
}

// Round 2
// 92.467 us; speedup vs baseline: 1.2376x; 1.2376x over previous
//
#include <hip/hip_runtime.h>
#include <math.h>

#define GL_ORDER 10

// Fast acos: Abramowitz-Stegun 4.4.45, |err| <= 5e-5 rad over [-1,1].
// acos(x) = sqrt(1-x)*(a0 + a1 x + a2 x^2 + a3 x^3) for x in [0,1];
// acos(x) = pi - acos(-x) for x < 0.
__device__ __forceinline__ float acos_fast(float x) {
    const float ax = fabsf(x);
    const float s  = __builtin_amdgcn_sqrtf(1.0f - ax);
    const float p  = fmaf(ax, fmaf(ax, fmaf(ax, -0.0187293f, 0.0742610f),
                                   -0.2121144f), 1.5707288f);
    const float r = s * p;
    return (x < 0.0f) ? (3.14159265358979323846f - r) : r;
}

__device__ __forceinline__ float lc_one(float b_in, float z, float r,
                                        float u0, float u1,
                                        float c_core, float c_ann,
                                        const float* tj, const float* wj,
                                        const float* wt) {
    const float bb = fabsf(b_in);

    // fully-occulted core: rho in [0, clip(r-b, 0, 1)]
    const float core_hi = fminf(fmaxf(r - bb, 0.0f), 1.0f);

    // partially-occulted annulus: rho in [clip(|b-r|,0,1), clip(b+r,0,1)]
    const float lo    = fminf(fabsf(bb - r), 1.0f);
    const float hi    = fminf(bb + r, 1.0f);
    const float width = fmaxf(hi - lo, 0.0f);

    const float b2r2 = fmaf(bb, bb, -r * r);  // b^2 - r^2
    const float twob = 2.0f * bb;

    float s_core = 0.0f;
    float s_ann  = 0.0f;

#pragma unroll
    for (int j = 0; j < GL_ORDER; ++j) {
        const float t = tj[j];

        // ---- core node: rho = core_hi * t ----
        const float rc   = core_hi * t;
        const float rc2  = rc * rc;
        const float muc  = __builtin_amdgcn_sqrtf(fmaxf(1.0f - rc2, 1e-12f));
        const float ommc = 1.0f - muc;
        const float Ic   = fmaf(-ommc, fmaf(u1, ommc, u0), 1.0f);
        s_core = fmaf(wt[j], Ic, s_core);  // wt = wj*tj prefolded

        // ---- annulus node: rho = lo + width * t ----
        const float ra   = fmaf(width, t, lo);
        const float ra2  = ra * ra;
        const float mua  = __builtin_amdgcn_sqrtf(fmaxf(1.0f - ra2, 1e-12f));
        const float omma = 1.0f - mua;
        const float Ia   = fmaf(-omma, fmaf(u1, omma, u0), 1.0f);

        // cosarg = (b^2 + rho^2 - r^2) / (2 b rho); rcp ~1ulp; clamp matches ref.
        const float cosarg_raw = (b2r2 + ra2) * __builtin_amdgcn_rcpf(twob * ra);
        const float cosarg = fminf(fmaxf(cosarg_raw, -0.999999f), 0.999999f);
        const float ac = acos_fast(cosarg);

        s_ann = fmaf(wj[j] * Ia, ac * ra, s_ann);
    }

    // lc = -(pi*ch^2*s_core + width*s_ann) / norm  (2*acos and 2pi prefolded)
    const float lc = fmaf(c_core * core_hi * core_hi, s_core,
                          c_ann * width * s_ann);
    return (z > 0.0f) ? lc : 0.0f;
}

__global__ __launch_bounds__(256) void LimbDarkLightCurve_55370718380097_kernel(
    const float* __restrict__ u, const float* __restrict__ bptr,
    const float* __restrict__ rptr, const float* __restrict__ zptr,
    float* __restrict__ out, int K) {
    // Order-10 GL nodes mapped to t = 0.5*(x+1); weights as-is; wt = w*t.
    const float tj[GL_ORDER] = {
        0.013046735741414128f, 0.067468316655507744f, 0.160295215850487787f,
        0.283302302935376393f, 0.425562830509184362f, 0.574437169490815638f,
        0.716697697064623607f, 0.839704784149512213f, 0.932531683344492256f,
        0.986953264258585872f};
    const float wj[GL_ORDER] = {
        0.066671344308688138f, 0.149451349150580593f, 0.219086362515982044f,
        0.269266719309996355f, 0.295524224714752870f, 0.295524224714752870f,
        0.269266719309996355f, 0.219086362515982044f, 0.149451349150580593f,
        0.066671344308688138f};
    float wt[GL_ORDER];
#pragma unroll
    for (int j = 0; j < GL_ORDER; ++j) wt[j] = wj[j] * tj[j];

    const float u0 = u[0];
    const float u1 = u[1];
    const float r  = rptr[0];
    // norm = pi * (1 - u0/3 - u1/6)
    const float inv_norm =
        1.0f / (3.14159265358979323846f *
                (1.0f - u0 * (1.0f / 3.0f) - u1 * (1.0f / 6.0f)));
    const float c_core = -3.14159265358979323846f * inv_norm;  // -(pi)/norm
    const float c_ann  = -inv_norm;                            // folded 2*acos & 0.5

    const int i4 = (blockIdx.x * blockDim.x + threadIdx.x) * 4;
    if (i4 + 3 < K) {
        const float4 b4 = *reinterpret_cast<const float4*>(bptr + i4);
        const float4 z4 = *reinterpret_cast<const float4*>(zptr + i4);
        float4 o;
        o.x = lc_one(b4.x, z4.x, r, u0, u1, c_core, c_ann, tj, wj, wt);
        o.y = lc_one(b4.y, z4.y, r, u0, u1, c_core, c_ann, tj, wj, wt);
        o.z = lc_one(b4.z, z4.z, r, u0, u1, c_core, c_ann, tj, wj, wt);
        o.w = lc_one(b4.w, z4.w, r, u0, u1, c_core, c_ann, tj, wj, wt);
        *reinterpret_cast<float4*>(out + i4) = o;
    } else {
        for (int i = i4; i < K; ++i) {
            out[i] = lc_one(bptr[i], zptr[i], r, u0, u1, c_core, c_ann, tj, wj, wt);
        }
    }
}

extern "C" void kernel_launch(void* const* d_in, const int* in_sizes, int n_in,
                              void* d_out, int out_size, void* d_ws, size_t ws_size,
                              hipStream_t stream) {
    const float* u = (const float*)d_in[0];
    const float* b = (const float*)d_in[1];
    const float* r = (const float*)d_in[2];
    const float* z = (const float*)d_in[3];
    float* out = (float*)d_out;
    const int K = in_sizes[1];

    const int elems_per_thread = 4;
    const int block = 256;
    const int threads_needed = (K + elems_per_thread - 1) / elems_per_thread;
    const int grid = (threads_needed + block - 1) / block;
    LimbDarkLightCurve_55370718380097_kernel<<<grid, block, 0, stream>>>(
        u, b, r, z, out, K);
}

// Round 3
// 88.717 us; speedup vs baseline: 1.2899x; 1.0423x over previous
//
#include <hip/hip_runtime.h>
#include <math.h>

#define GL_ORDER 10
#define TAB_N 65536              // intervals over [0, BMAX]
#define BMAX 1.3f

// Fast acos: Abramowitz-Stegun 4.4.45, |err| <= 5e-5 rad over [-1,1].
__device__ __forceinline__ float acos_fast(float x) {
    const float ax = fabsf(x);
    const float s  = __builtin_amdgcn_sqrtf(1.0f - ax);
    const float p  = fmaf(ax, fmaf(ax, fmaf(ax, -0.0187293f, 0.0742610f),
                                   -0.2121144f), 1.5707288f);
    const float r = s * p;
    return (x < 0.0f) ? (3.14159265358979323846f - r) : r;
}

// Full quadrature evaluation of lc(|b|) (no z mask).
__device__ float lc_eval(float bb, float r, float u0, float u1,
                         float c_core, float c_ann) {
    const float tj[GL_ORDER] = {
        0.013046735741414128f, 0.067468316655507744f, 0.160295215850487787f,
        0.283302302935376393f, 0.425562830509184362f, 0.574437169490815638f,
        0.716697697064623607f, 0.839704784149512213f, 0.932531683344492256f,
        0.986953264258585872f};
    const float wj[GL_ORDER] = {
        0.066671344308688138f, 0.149451349150580593f, 0.219086362515982044f,
        0.269266719309996355f, 0.295524224714752870f, 0.295524224714752870f,
        0.269266719309996355f, 0.219086362515982044f, 0.149451349150580593f,
        0.066671344308688138f};

    const float core_hi = fminf(fmaxf(r - bb, 0.0f), 1.0f);
    const float lo    = fminf(fabsf(bb - r), 1.0f);
    const float hi    = fminf(bb + r, 1.0f);
    const float width = fmaxf(hi - lo, 0.0f);

    const float b2r2 = fmaf(bb, bb, -r * r);
    const float twob = 2.0f * bb;

    float s_core = 0.0f;
    float s_ann  = 0.0f;

#pragma unroll
    for (int j = 0; j < GL_ORDER; ++j) {
        const float t = tj[j];

        const float rc   = core_hi * t;
        const float muc  = __builtin_amdgcn_sqrtf(fmaxf(fmaf(-rc, rc, 1.0f), 1e-12f));
        const float ommc = 1.0f - muc;
        const float Ic   = fmaf(-ommc, fmaf(u1, ommc, u0), 1.0f);
        s_core = fmaf(wj[j] * t, Ic, s_core);

        const float ra   = fmaf(width, t, lo);
        const float ra2  = ra * ra;
        const float mua  = __builtin_amdgcn_sqrtf(fmaxf(1.0f - ra2, 1e-12f));
        const float omma = 1.0f - mua;
        const float Ia   = fmaf(-omma, fmaf(u1, omma, u0), 1.0f);

        const float cosarg_raw = (b2r2 + ra2) * __builtin_amdgcn_rcpf(twob * ra);
        const float cosarg = fminf(fmaxf(cosarg_raw, -0.999999f), 0.999999f);
        const float ac = acos_fast(cosarg);

        s_ann = fmaf(wj[j] * Ia, ac * ra, s_ann);
    }

    return fmaf(c_core * core_hi * core_hi, s_core, c_ann * width * s_ann);
}

// Kernel 1: build the lc(|b|) table. table[i] = {lc(b_i), lc(b_{i+1})}.
// Thread i computes v = lc(i*h) and writes table[i].x = v, table[i-1].y = v.
__global__ __launch_bounds__(256) void lc_table_build(
    const float* __restrict__ u, const float* __restrict__ rptr,
    float2* __restrict__ table) {
    const int i = blockIdx.x * blockDim.x + threadIdx.x;
    if (i > TAB_N) return;

    const float u0 = u[0];
    const float u1 = u[1];
    const float r  = rptr[0];
    const float inv_norm =
        1.0f / (3.14159265358979323846f *
                (1.0f - u0 * (1.0f / 3.0f) - u1 * (1.0f / 6.0f)));
    const float c_core = -3.14159265358979323846f * inv_norm;
    const float c_ann  = -inv_norm;

    const float bb = (float)i * (BMAX / (float)TAB_N);
    const float v  = lc_eval(bb, r, u0, u1, c_core, c_ann);

    float* tf = (float*)table;
    if (i < TAB_N) tf[2 * i] = v;          // table[i].x
    if (i > 0)     tf[2 * i - 1] = v;      // table[i-1].y
}

// Kernel 2: per-sample lookup + linear interpolation + z mask.
__global__ __launch_bounds__(256) void LimbDarkLightCurve_55370718380097_kernel(
    const float* __restrict__ bptr, const float* __restrict__ zptr,
    const float2* __restrict__ table, float* __restrict__ out, int K) {
    const float scale = (float)TAB_N / BMAX;

    const int i4 = (blockIdx.x * blockDim.x + threadIdx.x) * 4;
    if (i4 + 3 < K) {
        const float4 b4 = *reinterpret_cast<const float4*>(bptr + i4);
        const float4 z4 = *reinterpret_cast<const float4*>(zptr + i4);
        float bs[4] = {b4.x, b4.y, b4.z, b4.w};
        float zs[4] = {z4.x, z4.y, z4.z, z4.w};
        float os[4];
#pragma unroll
        for (int k = 0; k < 4; ++k) {
            const float x = fminf(fabsf(bs[k]) * scale, (float)(TAB_N - 1));
            const int   i = (int)x;
            const float f = x - (float)i;
            const float2 tv = table[i];
            const float v = fmaf(f, tv.y - tv.x, tv.x);
            os[k] = (zs[k] > 0.0f) ? v : 0.0f;
        }
        float4 o = {os[0], os[1], os[2], os[3]};
        *reinterpret_cast<float4*>(out + i4) = o;
    } else {
        for (int i = i4; i < K; ++i) {
            const float x = fminf(fabsf(bptr[i]) * scale, (float)(TAB_N - 1));
            const int   ii = (int)x;
            const float f = x - (float)ii;
            const float2 tv = table[ii];
            const float v = fmaf(f, tv.y - tv.x, tv.x);
            out[i] = (zptr[i] > 0.0f) ? v : 0.0f;
        }
    }
}

// Fallback: direct evaluation (round-2 kernel) if d_ws is too small.
__global__ __launch_bounds__(256) void lc_direct_kernel(
    const float* __restrict__ u, const float* __restrict__ bptr,
    const float* __restrict__ rptr, const float* __restrict__ zptr,
    float* __restrict__ out, int K) {
    const float u0 = u[0];
    const float u1 = u[1];
    const float r  = rptr[0];
    const float inv_norm =
        1.0f / (3.14159265358979323846f *
                (1.0f - u0 * (1.0f / 3.0f) - u1 * (1.0f / 6.0f)));
    const float c_core = -3.14159265358979323846f * inv_norm;
    const float c_ann  = -inv_norm;

    const int i4 = (blockIdx.x * blockDim.x + threadIdx.x) * 4;
    for (int i = i4; i < K && i < i4 + 4; ++i) {
        const float v = lc_eval(fabsf(bptr[i]), r, u0, u1, c_core, c_ann);
        out[i] = (zptr[i] > 0.0f) ? v : 0.0f;
    }
}

extern "C" void kernel_launch(void* const* d_in, const int* in_sizes, int n_in,
                              void* d_out, int out_size, void* d_ws, size_t ws_size,
                              hipStream_t stream) {
    const float* u = (const float*)d_in[0];
    const float* b = (const float*)d_in[1];
    const float* r = (const float*)d_in[2];
    const float* z = (const float*)d_in[3];
    float* out = (float*)d_out;
    const int K = in_sizes[1];

    const int block = 256;
    const int grid_main = (K / 4 + block - 1) / block;

    const size_t tab_bytes = (size_t)TAB_N * sizeof(float2);
    if (ws_size >= tab_bytes) {
        float2* table = (float2*)d_ws;
        const int grid_tab = (TAB_N + 1 + block - 1) / block;
        lc_table_build<<<grid_tab, block, 0, stream>>>(u, r, table);
        LimbDarkLightCurve_55370718380097_kernel<<<grid_main, block, 0, stream>>>(
            b, z, table, out, K);
    } else {
        lc_direct_kernel<<<grid_main, block, 0, stream>>>(u, b, r, z, out, K);
    }
}

// Round 5
// 78.246 us; speedup vs baseline: 1.4625x; 1.1338x over previous
//
#include <hip/hip_runtime.h>
#include <math.h>

#define GL_ORDER 10
#define TAB_N 512                // intervals over [0, BMAX]; node table = 513 floats in LDS
#define BMAX 1.3f
#define BLOCK 256
#define CHUNKS 2                 // float4 chunks per thread
#define ELEMS_PER_BLOCK (BLOCK * 4 * CHUNKS)   // 2048

// Fast acos: Abramowitz-Stegun 4.4.45, |err| <= 5e-5 rad over [-1,1].
__device__ __forceinline__ float acos_fast(float x) {
    const float ax = fabsf(x);
    const float s  = __builtin_amdgcn_sqrtf(1.0f - ax);
    const float p  = fmaf(ax, fmaf(ax, fmaf(ax, -0.0187293f, 0.0742610f),
                                   -0.2121144f), 1.5707288f);
    const float r = s * p;
    return (x < 0.0f) ? (3.14159265358979323846f - r) : r;
}

// Full quadrature evaluation of lc(|b|) (no z mask).
__device__ float lc_eval(float bb, float r, float u0, float u1,
                         float c_core, float c_ann) {
    const float tj[GL_ORDER] = {
        0.013046735741414128f, 0.067468316655507744f, 0.160295215850487787f,
        0.283302302935376393f, 0.425562830509184362f, 0.574437169490815638f,
        0.716697697064623607f, 0.839704784149512213f, 0.932531683344492256f,
        0.986953264258585872f};
    const float wj[GL_ORDER] = {
        0.066671344308688138f, 0.149451349150580593f, 0.219086362515982044f,
        0.269266719309996355f, 0.295524224714752870f, 0.295524224714752870f,
        0.269266719309996355f, 0.219086362515982044f, 0.149451349150580593f,
        0.066671344308688138f};

    const float core_hi = fminf(fmaxf(r - bb, 0.0f), 1.0f);
    const float lo    = fminf(fabsf(bb - r), 1.0f);
    const float hi    = fminf(bb + r, 1.0f);
    const float width = fmaxf(hi - lo, 0.0f);

    const float b2r2 = fmaf(bb, bb, -r * r);
    const float twob = 2.0f * bb;

    float s_core = 0.0f;
    float s_ann  = 0.0f;

#pragma unroll
    for (int j = 0; j < GL_ORDER; ++j) {
        const float t = tj[j];

        const float rc   = core_hi * t;
        const float muc  = __builtin_amdgcn_sqrtf(fmaxf(fmaf(-rc, rc, 1.0f), 1e-12f));
        const float ommc = 1.0f - muc;
        const float Ic   = fmaf(-ommc, fmaf(u1, ommc, u0), 1.0f);
        s_core = fmaf(wj[j] * t, Ic, s_core);

        const float ra   = fmaf(width, t, lo);
        const float ra2  = ra * ra;
        const float mua  = __builtin_amdgcn_sqrtf(fmaxf(1.0f - ra2, 1e-12f));
        const float omma = 1.0f - mua;
        const float Ia   = fmaf(-omma, fmaf(u1, omma, u0), 1.0f);

        const float cosarg_raw = (b2r2 + ra2) * __builtin_amdgcn_rcpf(twob * ra);
        const float cosarg = fminf(fmaxf(cosarg_raw, -0.999999f), 0.999999f);
        const float ac = acos_fast(cosarg);

        s_ann = fmaf(wj[j] * Ia, ac * ra, s_ann);
    }

    return fmaf(c_core * core_hi * core_hi, s_core, c_ann * width * s_ann);
}

// Single fused kernel: build the lc table in LDS (per block), then stream
// elements with an LDS lookup + lerp + z-mask. No d_ws usage at all — the
// harness's workspace re-poison cannot touch our state.
__global__ __launch_bounds__(BLOCK) void LimbDarkLightCurve_55370718380097_kernel(
    const float* __restrict__ u, const float* __restrict__ bptr,
    const float* __restrict__ rptr, const float* __restrict__ zptr,
    float* __restrict__ out, int K) {
    __shared__ float fnode[TAB_N + 1];

    const float u0 = u[0];
    const float u1 = u[1];
    const float r  = rptr[0];
    const float inv_norm =
        1.0f / (3.14159265358979323846f *
                (1.0f - u0 * (1.0f / 3.0f) - u1 * (1.0f / 6.0f)));
    const float c_core = -3.14159265358979323846f * inv_norm;
    const float c_ann  = -inv_norm;

    // ---- build phase: 513 nodes, 2 per thread (+1 extra on thread 0) ----
    const float hstep = BMAX / (float)TAB_N;
    for (int node = threadIdx.x; node <= TAB_N; node += BLOCK) {
        fnode[node] = lc_eval((float)node * hstep, r, u0, u1, c_core, c_ann);
    }
    __syncthreads();

    // ---- lookup phase ----
    const float scale = (float)TAB_N / BMAX;
    const int base = blockIdx.x * ELEMS_PER_BLOCK;

#pragma unroll
    for (int c = 0; c < CHUNKS; ++c) {
        const int i4 = base + (threadIdx.x + c * BLOCK) * 4;
        if (i4 + 3 < K) {
            const float4 b4 = *reinterpret_cast<const float4*>(bptr + i4);
            const float4 z4 = *reinterpret_cast<const float4*>(zptr + i4);
            float bs[4] = {b4.x, b4.y, b4.z, b4.w};
            float zs[4] = {z4.x, z4.y, z4.z, z4.w};
            float os[4];
#pragma unroll
            for (int k = 0; k < 4; ++k) {
                const float x = fabsf(bs[k]) * scale;
                int   i = (int)x;
                i = (i < TAB_N - 1) ? i : (TAB_N - 1);
                const float f  = x - (float)i;
                const float v0 = fnode[i];
                const float v1 = fnode[i + 1];
                const float v  = fmaf(f, v1 - v0, v0);
                os[k] = (zs[k] > 0.0f) ? v : 0.0f;
            }
            float4 o = {os[0], os[1], os[2], os[3]};
            *reinterpret_cast<float4*>(out + i4) = o;
        } else {
            for (int i = i4; i < K; ++i) {
                const float x = fabsf(bptr[i]) * scale;
                int   ii = (int)x;
                ii = (ii < TAB_N - 1) ? ii : (TAB_N - 1);
                const float f  = x - (float)ii;
                const float v0 = fnode[ii];
                const float v1 = fnode[ii + 1];
                const float v  = fmaf(f, v1 - v0, v0);
                out[i] = (zptr[i] > 0.0f) ? v : 0.0f;
            }
        }
    }
}

extern "C" void kernel_launch(void* const* d_in, const int* in_sizes, int n_in,
                              void* d_out, int out_size, void* d_ws, size_t ws_size,
                              hipStream_t stream) {
    const float* u = (const float*)d_in[0];
    const float* b = (const float*)d_in[1];
    const float* r = (const float*)d_in[2];
    const float* z = (const float*)d_in[3];
    float* out = (float*)d_out;
    const int K = in_sizes[1];

    const int grid = (K + ELEMS_PER_BLOCK - 1) / ELEMS_PER_BLOCK;
    LimbDarkLightCurve_55370718380097_kernel<<<grid, BLOCK, 0, stream>>>(
        u, b, r, z, out, K);
}